// Round 4
// baseline (338.763 us; speedup 1.0000x reference)
//
#include <hip/hip_runtime.h>
#include <float.h>

#define N_NODES 50000
#define N_EDGES 600000
#define D 128
#define N_GRAPHS 64
#define SCAN_T 256
#define SCAN_NBLK ((N_NODES + SCAN_T - 1) / SCAN_T)   // 196

typedef __attribute__((ext_vector_type(8))) short short8;   // 8 bf16 = 4 VGPRs
typedef __attribute__((ext_vector_type(4))) float floatx4;

__device__ inline float bf2f(unsigned short h) {
    return __uint_as_float((unsigned)h << 16);
}
__device__ inline unsigned short f2bf(float f) {
    unsigned u = __float_as_uint(f);
    return (unsigned short)((u + 0x7fffu + ((u >> 16) & 1u)) >> 16);   // RNE
}

// ---- i8 helpers: 8 bytes (int2) -> f32 accumulate / bf16 frag -----------------

__device__ inline void acc8v(int2 u, float ss, float* a) {
    a[0] += (float)(signed char)(u.x      ) * ss;
    a[1] += (float)(signed char)(u.x >>  8) * ss;
    a[2] += (float)(signed char)(u.x >> 16) * ss;
    a[3] += (float)(u.x >> 24)              * ss;
    a[4] += (float)(signed char)(u.y      ) * ss;
    a[5] += (float)(signed char)(u.y >>  8) * ss;
    a[6] += (float)(signed char)(u.y >> 16) * ss;
    a[7] += (float)(u.y >> 24)              * ss;
}

__device__ inline short8 deq8(int2 u, float ss) {
    short8 r;
    r[0] = (short)f2bf((float)(signed char)(u.x      ) * ss);
    r[1] = (short)f2bf((float)(signed char)(u.x >>  8) * ss);
    r[2] = (short)f2bf((float)(signed char)(u.x >> 16) * ss);
    r[3] = (short)f2bf((float)(u.x >> 24)              * ss);
    r[4] = (short)f2bf((float)(signed char)(u.y      ) * ss);
    r[5] = (short)f2bf((float)(signed char)(u.y >>  8) * ss);
    r[6] = (short)f2bf((float)(signed char)(u.y >> 16) * ss);
    r[7] = (short)f2bf((float)(u.y >> 24)              * ss);
    return r;
}

// ------- prep: x -> i8(+scale), weights -> Bb, zero deg, init g ----------------
// Bb[o][k] row-major-in-k IS the MFMA B-fragment layout (n fixed, k contiguous).

__global__ __launch_bounds__(256) void cast_prep(
    const float* __restrict__ x,
    signed char* __restrict__ xq, float* __restrict__ xs,
    const float* __restrict__ Wr0, const float* __restrict__ Wo0,
    const float* __restrict__ Wr1, const float* __restrict__ Wo1,
    const float* __restrict__ Wr2, const float* __restrict__ Wo2,
    unsigned short* __restrict__ B0, unsigned short* __restrict__ B1,
    unsigned short* __restrict__ B2,
    int* __restrict__ deg, float* __restrict__ g)
{
    int t = blockIdx.x * 256 + threadIdx.x;
    if (t < N_NODES * 16) {
        int node = t >> 4, ln = t & 15;
        const float4* xr = (const float4*)(x + (size_t)node * D + ln * 8);
        float4 v0 = xr[0], v1 = xr[1];
        float v[8] = {v0.x, v0.y, v0.z, v0.w, v1.x, v1.y, v1.z, v1.w};
        float am = 0.f;
#pragma unroll
        for (int i = 0; i < 8; ++i) am = fmaxf(am, fabsf(v[i]));
#pragma unroll
        for (int m = 1; m < 16; m <<= 1) am = fmaxf(am, __shfl_xor(am, m, 16));
        float inv = (am > 0.f) ? 127.f / am : 0.f;
        int q0 = 0, q1 = 0;
#pragma unroll
        for (int i = 0; i < 4; ++i) { int q = (int)rintf(v[i]     * inv); q0 |= (q & 0xff) << (8 * i); }
#pragma unroll
        for (int i = 0; i < 4; ++i) { int q = (int)rintf(v[4 + i] * inv); q1 |= (q & 0xff) << (8 * i); }
        int2 qp; qp.x = q0; qp.y = q1;
        *(int2*)(xq + (size_t)node * D + ln * 8) = qp;
        if (ln == 0) xs[node] = am * (1.f / 127.f);
        return;
    }
    int w = t - N_NODES * 16;
    if (w < 3 * 128 * 256) {
        int l = w >> 15;
        int r = w & 32767;
        int o = r >> 8, k = r & 255;
        const float* Wr = (l == 0) ? Wr0 : (l == 1) ? Wr1 : Wr2;
        const float* Wo = (l == 0) ? Wo0 : (l == 1) ? Wo1 : Wo2;
        unsigned short* B = (l == 0) ? B0 : (l == 1) ? B1 : B2;
        float v = (k < 128) ? Wr[o * 128 + k] : Wo[o * 128 + (k - 128)];
        B[r] = f2bf(v);
        return;
    }
    w -= 3 * 128 * 256;
    if (w < N_NODES) { deg[w] = 0; return; }
    w -= N_NODES;
    if (w < N_GRAPHS * D) g[w] = -FLT_MAX;
}

// ---------------- CSR build (once per launch) ----------------------------------

__global__ void count_deg(const int* __restrict__ ei, int* __restrict__ deg) {
    int e = blockIdx.x * 256 + threadIdx.x;
    if (e < N_EDGES) atomicAdd(&deg[ei[N_EDGES + e]], 1);
}

__global__ __launch_bounds__(SCAN_T) void block_sum(const int* __restrict__ deg,
                                                    int* __restrict__ blockSums) {
    __shared__ int s[SCAN_T];
    int tid = threadIdx.x;
    int i = blockIdx.x * SCAN_T + tid;
    s[tid] = (i < N_NODES) ? deg[i] : 0;
    __syncthreads();
    for (int off = SCAN_T / 2; off > 0; off >>= 1) {
        if (tid < off) s[tid] += s[tid + off];
        __syncthreads();
    }
    if (tid == 0) blockSums[blockIdx.x] = s[0];
}

__global__ __launch_bounds__(SCAN_T) void scan_write(const int* __restrict__ deg,
                                                     const int* __restrict__ blockSums,
                                                     int* __restrict__ row_start,
                                                     int* __restrict__ cursor) {
    __shared__ int bs[SCAN_T];
    __shared__ int s[SCAN_T];
    int tid = threadIdx.x;
    bs[tid] = (tid < SCAN_NBLK) ? blockSums[tid] : 0;
    __syncthreads();
    for (int off = 1; off < SCAN_T; off <<= 1) {
        int tt = (tid >= off) ? bs[tid - off] : 0;
        __syncthreads();
        bs[tid] += tt;
        __syncthreads();
    }
    int myOff = (blockIdx.x == 0) ? 0 : bs[blockIdx.x - 1];
    if (blockIdx.x == 0 && tid == SCAN_T - 1) row_start[N_NODES] = bs[tid];

    int i = blockIdx.x * SCAN_T + tid;
    int v = (i < N_NODES) ? deg[i] : 0;
    s[tid] = v;
    __syncthreads();
    for (int off = 1; off < SCAN_T; off <<= 1) {
        int tt = (tid >= off) ? s[tid - off] : 0;
        __syncthreads();
        s[tid] += tt;
        __syncthreads();
    }
    if (i < N_NODES) {
        int rs = myOff + s[tid] - v;
        row_start[i] = rs;
        cursor[i]    = rs;
    }
}

__global__ void fill_csr(const int* __restrict__ ei, int* __restrict__ cursor,
                         int* __restrict__ csr_src) {
    int e = blockIdx.x * 256 + threadIdx.x;
    if (e < N_EDGES) {
        int dst = ei[N_EDGES + e];
        int pos = atomicAdd(&cursor[dst], 1);
        csr_src[pos] = ei[e];
    }
}

// ---------------- register gather: 4 lanes/node, frag-layout accumulate --------
// lane (m,quad) owns feats {quad*8 + 32*ks + j} of node row0+wave*16+m --
// exactly the MFMA A-fragment layout, so no LDS staging of A at all.

__device__ inline void gather_frag(const signed char* __restrict__ xq,
                                   const float* __restrict__ xs,
                                   const int* __restrict__ row_start,
                                   const int* __restrict__ csr_src,
                                   int node, int m, int quad, float* a)
{
#pragma unroll
    for (int i = 0; i < 32; ++i) a[i] = 0.f;
    if (node >= N_NODES) return;
    int beg = row_start[node];
    int end = row_start[node + 1];
    for (int base = beg; base < end; base += 4) {
        int n = end - base; if (n > 4) n = 4;
        int idx = (quad < n) ? csr_src[base + quad] : 0;   // coalesced index load
        for (int j = 0; j < n; ++j) {
            int s = __shfl(idx, m + 16 * j, 64);
            const signed char* rp = xq + (size_t)s * D + quad * 8;
            int2 q0 = *(const int2*)(rp);
            int2 q1 = *(const int2*)(rp + 32);
            int2 q2 = *(const int2*)(rp + 64);
            int2 q3 = *(const int2*)(rp + 96);
            float ss = xs[s];
            acc8v(q0, ss, a); acc8v(q1, ss, a + 8);
            acc8v(q2, ss, a + 16); acc8v(q3, ss, a + 24);
        }
    }
}

// ---------------- B staging: global -> LDS, MFMA-fragment order ----------------

__device__ inline void stage_b_half(unsigned short* sB, const unsigned short* __restrict__ Bb,
                                    int tid, int h) {
#pragma unroll
    for (int i = 0; i < 8; ++i) {
        int flat = tid + i * 256;            // 0..2047
        int fi = flat >> 6, ln = flat & 63;  // frag idx / lane
        int mm = ln & 15, qq = ln >> 4;
        int ksL = fi >> 3, tt = fi & 7;
        short8 v = *(const short8*)(Bb + (size_t)(tt * 16 + mm) * 256
                                    + (h * 4 + ksL) * 32 + qq * 8);
        *(short8*)(sB + (size_t)flat * 8) = v;
    }
}

// ---------------- fused layer: reg-gather -> MFMA -> i8 quant out --------------

struct GemmShared {
    union {
        unsigned short b[16384];   // 32 KB B-half
        float c[64 * 130];         // 33.3 KB C tile
    };
};

__global__ __launch_bounds__(256) void layer_fused(
    const signed char* __restrict__ xq, const float* __restrict__ xs,
    const int* __restrict__ row_start, const int* __restrict__ csr_src,
    const unsigned short* __restrict__ Bb, const float* __restrict__ bias,
    signed char* __restrict__ Oq, float* __restrict__ Os)
{
    __shared__ GemmShared sh;
    int tid  = threadIdx.x;
    int wave = tid >> 6;
    int lane = tid & 63;
    int m    = lane & 15;
    int quad = lane >> 4;
    int row0 = blockIdx.x * 64 + wave * 16;
    int node = row0 + m;

    float a[32];
    gather_frag(xq, xs, row_start, csr_src, node, m, quad, a);

    short8 afA[4];
#pragma unroll
    for (int ks = 0; ks < 4; ++ks) {
        short8 f;
#pragma unroll
        for (int j = 0; j < 8; ++j) f[j] = (short)f2bf(a[ks * 8 + j]);
        afA[ks] = f;
    }

    int arow = (node < N_NODES) ? node : N_NODES - 1;
    const signed char* xr = xq + (size_t)arow * D + quad * 8;
    float fsr = xs[arow];
    short8 afX[4];
    afX[0] = deq8(*(const int2*)(xr),      fsr);
    afX[1] = deq8(*(const int2*)(xr + 32), fsr);
    afX[2] = deq8(*(const int2*)(xr + 64), fsr);
    afX[3] = deq8(*(const int2*)(xr + 96), fsr);

    floatx4 acc[8];
#pragma unroll
    for (int t = 0; t < 8; ++t) acc[t] = (floatx4){0.f, 0.f, 0.f, 0.f};

    stage_b_half(sh.b, Bb, tid, 0);
    __syncthreads();
#pragma unroll
    for (int ksL = 0; ksL < 4; ++ksL)
#pragma unroll
        for (int t = 0; t < 8; ++t) {
            short8 b = *(const short8*)(sh.b + (size_t)((ksL * 8 + t) * 64 + lane) * 8);
            acc[t] = __builtin_amdgcn_mfma_f32_16x16x32_bf16(afA[ksL], b, acc[t], 0, 0, 0);
        }
    __syncthreads();
    stage_b_half(sh.b, Bb, tid, 1);
    __syncthreads();
#pragma unroll
    for (int ksL = 0; ksL < 4; ++ksL)
#pragma unroll
        for (int t = 0; t < 8; ++t) {
            short8 b = *(const short8*)(sh.b + (size_t)((ksL * 8 + t) * 64 + lane) * 8);
            acc[t] = __builtin_amdgcn_mfma_f32_16x16x32_bf16(afX[ksL], b, acc[t], 0, 0, 0);
        }
    __syncthreads();                         // all sB reads done; reuse as C tile

#pragma unroll
    for (int t = 0; t < 8; ++t) {
        int col = t * 16 + m;
        float bv = bias[col];
#pragma unroll
        for (int r = 0; r < 4; ++r)
            sh.c[(wave * 16 + quad * 4 + r) * 130 + col] = fmaxf(acc[t][r] + bv, 0.f);
    }
    __syncthreads();

    // quant + store: 4 threads/row, 32 contiguous cols each
    int lr  = tid >> 2;
    int seg = tid & 3;
    int grow = blockIdx.x * 64 + lr;
    const float* cp = &sh.c[lr * 130 + seg * 32];
    float vv[32];
    float am = 0.f;
#pragma unroll
    for (int i = 0; i < 32; ++i) { vv[i] = cp[i]; am = fmaxf(am, fabsf(vv[i])); }
    am = fmaxf(am, __shfl_xor(am, 1));
    am = fmaxf(am, __shfl_xor(am, 2));
    float inv = (am > 0.f) ? 127.f / am : 0.f;

    if (grow < N_NODES) {
        int qd[8];
#pragma unroll
        for (int d = 0; d < 8; ++d) {
            int q = 0;
#pragma unroll
            for (int i = 0; i < 4; ++i) {
                int qq = (int)rintf(vv[d * 4 + i] * inv);
                q |= (qq & 0xff) << (8 * i);
            }
            qd[d] = q;
        }
        int4 p0; p0.x = qd[0]; p0.y = qd[1]; p0.z = qd[2]; p0.w = qd[3];
        int4 p1; p1.x = qd[4]; p1.y = qd[5]; p1.z = qd[6]; p1.w = qd[7];
        *(int4*)(Oq + (size_t)grow * 128 + seg * 32)      = p0;
        *(int4*)(Oq + (size_t)grow * 128 + seg * 32 + 16) = p1;
        if (seg == 0) Os[grow] = am * (1.f / 127.f);
    }
}

// ---------------- fused layer-3: reg-gather -> MFMA -> pooled max --------------

struct PoolShared {
    union {
        unsigned short b[16384];     // 32 KB B-half
        float c[64 * 129];           // 33 KB C tile
    };
};

__global__ __launch_bounds__(256) void layer_pool(
    const signed char* __restrict__ xq, const float* __restrict__ xs,
    const int* __restrict__ row_start, const int* __restrict__ csr_src,
    const unsigned short* __restrict__ Bb, const float* __restrict__ bias,
    const int* __restrict__ batch, float* __restrict__ g)
{
    __shared__ PoolShared sh;
    __shared__ int bl[64];
    int tid  = threadIdx.x;
    int wave = tid >> 6;
    int lane = tid & 63;
    int m    = lane & 15;
    int quad = lane >> 4;
    int row0 = blockIdx.x * 64;
    int node = row0 + wave * 16 + m;

    float a[32];
    gather_frag(xq, xs, row_start, csr_src, node, m, quad, a);

    short8 afA[4];
#pragma unroll
    for (int ks = 0; ks < 4; ++ks) {
        short8 f;
#pragma unroll
        for (int j = 0; j < 8; ++j) f[j] = (short)f2bf(a[ks * 8 + j]);
        afA[ks] = f;
    }

    int arow = (node < N_NODES) ? node : N_NODES - 1;
    const signed char* xr = xq + (size_t)arow * D + quad * 8;
    float fsr = xs[arow];
    short8 afX[4];
    afX[0] = deq8(*(const int2*)(xr),      fsr);
    afX[1] = deq8(*(const int2*)(xr + 32), fsr);
    afX[2] = deq8(*(const int2*)(xr + 64), fsr);
    afX[3] = deq8(*(const int2*)(xr + 96), fsr);

    floatx4 acc[8];
#pragma unroll
    for (int t = 0; t < 8; ++t) acc[t] = (floatx4){0.f, 0.f, 0.f, 0.f};

    if (tid < 64) {
        int grow = row0 + tid;
        bl[tid] = (grow < N_NODES) ? batch[grow] : -1;
    }
    stage_b_half(sh.b, Bb, tid, 0);
    __syncthreads();
#pragma unroll
    for (int ksL = 0; ksL < 4; ++ksL)
#pragma unroll
        for (int t = 0; t < 8; ++t) {
            short8 b = *(const short8*)(sh.b + (size_t)((ksL * 8 + t) * 64 + lane) * 8);
            acc[t] = __builtin_amdgcn_mfma_f32_16x16x32_bf16(afA[ksL], b, acc[t], 0, 0, 0);
        }
    __syncthreads();
    stage_b_half(sh.b, Bb, tid, 1);
    __syncthreads();
#pragma unroll
    for (int ksL = 0; ksL < 4; ++ksL)
#pragma unroll
        for (int t = 0; t < 8; ++t) {
            short8 b = *(const short8*)(sh.b + (size_t)((ksL * 8 + t) * 64 + lane) * 8);
            acc[t] = __builtin_amdgcn_mfma_f32_16x16x32_bf16(afX[ksL], b, acc[t], 0, 0, 0);
        }
    __syncthreads();                         // all sB reads done; reuse as C tile

#pragma unroll
    for (int t = 0; t < 8; ++t) {
        int col = t * 16 + m;
        float bv = bias[col];
#pragma unroll
        for (int r = 0; r < 4; ++r)
            sh.c[(wave * 16 + quad * 4 + r) * 129 + col] = acc[t][r] + bv;
    }
    __syncthreads();

    int nvalid = min(64, N_NODES - row0);
    int b0 = bl[0], b1 = bl[nvalid - 1];     // batch sorted; 1-3 graphs per block
    int col  = tid & 127;
    int rbeg = (tid >> 7) * 32;
    for (int gg = b0; gg <= b1; ++gg) {
        float cur = -FLT_MAX;
#pragma unroll
        for (int r = 0; r < 32; ++r) {
            int rr = rbeg + r;
            float v = (bl[rr] == gg) ? sh.c[rr * 129 + col] : -FLT_MAX;
            cur = fmaxf(cur, v);
        }
        if (cur > -FLT_MAX) {
            float* ad = &g[gg * D + col];
            if (cur >= 0.f) atomicMax((int*)ad, __float_as_int(cur));
            else            atomicMin((unsigned int*)ad, __float_as_uint(cur));
        }
    }
}

// ---------------- head: one wave per graph -------------------------------------

__global__ __launch_bounds__(64) void mlp_head(const float* __restrict__ g,
                         const float* __restrict__ W1, const float* __restrict__ b1,
                         const float* __restrict__ W2, const float* __restrict__ b2,
                         float* __restrict__ out) {
    int gi = blockIdx.x;
    int lane = threadIdx.x;
    float x0 = g[gi * D + lane];
    float x1 = g[gi * D + 64 + lane];
    float o = b2[0];
#pragma unroll
    for (int j = 0; j < 5; ++j) {
        float p = x0 * W1[j * D + lane] + x1 * W1[j * D + 64 + lane];
#pragma unroll
        for (int off = 32; off > 0; off >>= 1) p += __shfl_xor(p, off, 64);
        o += fmaxf(p + b1[j], 0.f) * W2[j];
    }
    if (lane == 0) out[gi] = o;
}

extern "C" void kernel_launch(void* const* d_in, const int* in_sizes, int n_in,
                              void* d_out, int out_size, void* d_ws, size_t ws_size,
                              hipStream_t stream) {
    const float* x     = (const float*)d_in[0];
    const int*   ei    = (const int*)d_in[1];
    const int*   batch = (const int*)d_in[2];
    const float* Wrel[3]  = {(const float*)d_in[3], (const float*)d_in[6], (const float*)d_in[9]};
    const float* brel[3]  = {(const float*)d_in[4], (const float*)d_in[7], (const float*)d_in[10]};
    const float* Wroot[3] = {(const float*)d_in[5], (const float*)d_in[8], (const float*)d_in[11]};
    const float* W1 = (const float*)d_in[12];
    const float* b1 = (const float*)d_in[13];
    const float* W2 = (const float*)d_in[14];
    const float* b2 = (const float*)d_in[15];
    float* out = (float*)d_out;

    char* ws = (char*)d_ws;
    const size_t nodeB8 = (size_t)N_NODES * D;                            // 6.4 MB
    signed char* xq  = (signed char*)(ws);
    signed char* h1q = (signed char*)(ws + 1 * nodeB8);
    signed char* h2q = (signed char*)(ws + 2 * nodeB8);
    char* p = ws + 3 * nodeB8;
    float* xs  = (float*)p;  p += N_NODES * sizeof(float);
    float* h1s = (float*)p;  p += N_NODES * sizeof(float);
    float* h2s = (float*)p;  p += N_NODES * sizeof(float);
    unsigned short* Bb0 = (unsigned short*)p;   p += 128 * 256 * sizeof(unsigned short);
    unsigned short* Bb1 = (unsigned short*)p;   p += 128 * 256 * sizeof(unsigned short);
    unsigned short* Bb2 = (unsigned short*)p;   p += 128 * 256 * sizeof(unsigned short);
    float* g        = (float*)p;                p += N_GRAPHS * D * sizeof(float);
    int*   deg      = (int*)p;                  p += N_NODES * sizeof(int);
    int*   row_start= (int*)p;                  p += (N_NODES + 1) * sizeof(int);
    int*   cursor   = (int*)p;                  p += N_NODES * sizeof(int);
    int*   csr_src  = (int*)p;                  p += N_EDGES * sizeof(int);
    int*   blockSums= (int*)p;                  p += SCAN_NBLK * sizeof(int);

    // prep: i8 cast + weight packs + zero deg + init g
    const int cast_total = N_NODES * 16 + 3 * 128 * 256 + N_NODES + N_GRAPHS * D;
    cast_prep<<<(cast_total + 255) / 256, 256, 0, stream>>>(
        x, xq, xs,
        Wrel[0], Wroot[0], Wrel[1], Wroot[1], Wrel[2], Wroot[2],
        Bb0, Bb1, Bb2, deg, g);

    // CSR build (once per call)
    count_deg<<<(N_EDGES + 255) / 256, 256, 0, stream>>>(ei, deg);
    block_sum<<<SCAN_NBLK, SCAN_T, 0, stream>>>(deg, blockSums);
    scan_write<<<SCAN_NBLK, SCAN_T, 0, stream>>>(deg, blockSums, row_start, cursor);
    fill_csr<<<(N_EDGES + 255) / 256, 256, 0, stream>>>(ei, cursor, csr_src);

    const int mgrid = (N_NODES + 63) / 64;                // 782

    layer_fused<<<mgrid, 256, 0, stream>>>(xq,  xs,  row_start, csr_src, Bb0, brel[0], h1q, h1s);
    layer_fused<<<mgrid, 256, 0, stream>>>(h1q, h1s, row_start, csr_src, Bb1, brel[1], h2q, h2s);
    layer_pool <<<mgrid, 256, 0, stream>>>(h2q, h2s, row_start, csr_src, Bb2, brel[2], batch, g);

    mlp_head<<<N_GRAPHS, 64, 0, stream>>>(g, W1, b1, W2, b2, out);
}